// Round 1
// baseline (598.216 us; speedup 1.0000x reference)
//
#include <hip/hip_runtime.h>

// ---------------------------------------------------------------------------
// MHA with softmax over the HEADS axis (torch legacy F.softmax dim=1).
// B=2, S=2048, D=1024, H=16, dh=64. scale = sqrt(1024) = 32.
//
// Pipeline:
//  1. convert_x : queries/keys/values f32 -> bf16          (ws Xb, 24 MB)
//  2. transpose_w: Wq,Wk,Wv,Wo f32 [K][N] -> bf16 Wt [N][K] (ws Wt, 8 MB)
//  3. gemm<0> x2: Qb, Kb = X @ W + b   (bf16 [4096][1024])
//     gemm<1>   : Vt = (Xv @ Wv + bv)^T per batch (bf16 [2][1024][2048])
//  4. attn      : per (qtile32, batch, khalf): 16-head scores, Z=sum_h exp,
//                 weights=exp/Z, O += W@V.  Partials (ksplit=2) -> bf16.
//  5. sum_o     : Ob = bf16(O0+O1)
//  6. gemm<2>   : out = Ob @ Wo + bo (f32)
// ws layout (56 MB total): [Xb 12M ushorts | Wt 4M | Qb 4M | Kb 4M | Vt 4M]
// O-partials (8M) and Ob (4M) alias Xb (dead by then).
// ---------------------------------------------------------------------------

typedef unsigned short ushort;
typedef __attribute__((ext_vector_type(8))) short short8;
typedef __attribute__((ext_vector_type(4))) short short4v;
typedef __attribute__((ext_vector_type(4))) float f32x4;
typedef __attribute__((ext_vector_type(4))) float float4v;
typedef __attribute__((ext_vector_type(4))) unsigned int uint4v;
typedef __attribute__((ext_vector_type(2))) unsigned int uint2v;

#define MFMA32(a, b, c) __builtin_amdgcn_mfma_f32_16x16x32_bf16(a, b, c, 0, 0, 0)
#define MFMA16(a, b, c) __builtin_amdgcn_mfma_f32_16x16x16bf16_1k(a, b, c, 0, 0, 0)

__device__ __forceinline__ ushort f2bf(float f) {  // round-to-nearest-even
    unsigned u = __float_as_uint(f);
    u += 0x7fffu + ((u >> 16) & 1u);
    return (ushort)(u >> 16);
}
__device__ __forceinline__ float bf2f(ushort u) {
    return __uint_as_float(((unsigned)u) << 16);
}

// ------------------------- 1. convert inputs to bf16 -----------------------
__global__ __launch_bounds__(256) void convert_x_kernel(
    const float* __restrict__ q, const float* __restrict__ k,
    const float* __restrict__ v, ushort* __restrict__ out) {
    const size_t NPER = 4194304ull;  // 4096*1024
    size_t idx = ((size_t)blockIdx.x * 256 + threadIdx.x) * 8;
    const size_t stride = (size_t)gridDim.x * 256 * 8;
    for (; idx < 3 * NPER; idx += stride) {
        const float* src;
        size_t off;
        if (idx < NPER)          { src = q; off = idx; }
        else if (idx < 2 * NPER) { src = k; off = idx - NPER; }
        else                     { src = v; off = idx - 2 * NPER; }
        float4v a = *(const float4v*)(src + off);
        float4v b = *(const float4v*)(src + off + 4);
        union { ushort u[8]; uint4v v4; } pk;
        #pragma unroll
        for (int j = 0; j < 4; j++) { pk.u[j] = f2bf(a[j]); pk.u[4 + j] = f2bf(b[j]); }
        *(uint4v*)(out + idx) = pk.v4;
    }
}

// ------------------- 2. transpose weights: [K][N] -> [N][K] bf16 -----------
__global__ __launch_bounds__(256) void transpose_w_kernel(
    const float* __restrict__ w0, const float* __restrict__ w1,
    const float* __restrict__ w2, const float* __restrict__ w3,
    ushort* __restrict__ Wt) {
    const float* W = blockIdx.z == 0 ? w0 : blockIdx.z == 1 ? w1 : blockIdx.z == 2 ? w2 : w3;
    ushort* out = Wt + (size_t)blockIdx.z * 1024 * 1024;
    __shared__ ushort st[64 * 72];
    int t = threadIdx.x;
    int kb = blockIdx.y * 64, nb = blockIdx.x * 64;
    int c4 = (t & 15) * 4;  // n offset within tile
    int r0 = t >> 4;
    #pragma unroll
    for (int p = 0; p < 4; p++) {
        int r = r0 + p * 16;  // k row within tile
        float4v f = *(const float4v*)(W + (size_t)(kb + r) * 1024 + nb + c4);
        union { ushort u[4]; uint2v v2; } pk;
        #pragma unroll
        for (int j = 0; j < 4; j++) pk.u[j] = f2bf(f[j]);
        *(uint2v*)(st + r * 72 + c4) = pk.v2;
    }
    __syncthreads();
    int n = t >> 2;
    int kc = (t & 3) * 16;
    union { ushort u[16]; uint4v v4[2]; } tw;
    #pragma unroll
    for (int j = 0; j < 16; j++) tw.u[j] = st[(kc + j) * 72 + n];
    uint4v* dst = (uint4v*)(out + (size_t)(nb + n) * 1024 + kb + kc);
    dst[0] = tw.v4[0];
    dst[1] = tw.v4[1];
}

// ------------------- 3./6. GEMM: C[M=4096][N=1024] = A[M][1024] * Bt[N][1024]^T
// MODE 0: bf16 row-major out.  MODE 1: bf16 transposed per batch (Vt[b][n][m]).
// MODE 2: f32 out + bias.  LDS XOR-swizzled (stride-128B tiles -> 2-way max).
template <int MODE>
__global__ __launch_bounds__(256, 2) void gemm_bt_kernel(
    const ushort* __restrict__ A, const ushort* __restrict__ Bt,
    const float* __restrict__ bias, ushort* __restrict__ Cb,
    float* __restrict__ Cf) {
    __shared__ ushort sA[128 * 64];
    __shared__ ushort sB[128 * 64];
    int tid = threadIdx.x, lane = tid & 63, wave = tid >> 6;
    int li = lane & 15, g = lane >> 4;
    int mt = blockIdx.y * 128, nt = blockIdx.x * 128;
    int wm = (wave >> 1) * 64, wn = (wave & 1) * 64;
    f32x4 acc[4][4] = {};
    for (int k0 = 0; k0 < 1024; k0 += 64) {
        #pragma unroll
        for (int i = 0; i < 4; i++) {
            int c = tid + i * 256;          // 0..1023 chunk id (16B chunks)
            int row = c >> 3, colb = (c & 7) * 16;
            int sw = colb ^ ((row & 7) << 4);
            *(uint4v*)((char*)sA + row * 128 + sw) =
                *(const uint4v*)(A + (size_t)(mt + row) * 1024 + k0 + (colb >> 1));
            *(uint4v*)((char*)sB + row * 128 + sw) =
                *(const uint4v*)(Bt + (size_t)(nt + row) * 1024 + k0 + (colb >> 1));
        }
        __syncthreads();
        #pragma unroll
        for (int kk = 0; kk < 2; kk++) {
            short8 af[4], bfr[4];
            #pragma unroll
            for (int i = 0; i < 4; i++) {
                int ra = wm + i * 16 + li;
                int cb = kk * 64 + g * 16;
                af[i] = *(const short8*)((char*)sA + ra * 128 + (cb ^ ((ra & 7) << 4)));
                int rb = wn + i * 16 + li;
                bfr[i] = *(const short8*)((char*)sB + rb * 128 + (cb ^ ((rb & 7) << 4)));
            }
            #pragma unroll
            for (int mi = 0; mi < 4; mi++)
                #pragma unroll
                for (int ni = 0; ni < 4; ni++)
                    acc[mi][ni] = MFMA32(af[mi], bfr[ni], acc[mi][ni]);
        }
        __syncthreads();
    }
    // epilogue: C tile layout col = lane&15 (n), row = g*4 + r (m)
    #pragma unroll
    for (int mi = 0; mi < 4; mi++) {
        #pragma unroll
        for (int ni = 0; ni < 4; ni++) {
            int n = nt + wn + ni * 16 + li;
            int m0 = mt + wm + mi * 16 + g * 4;
            float bv = bias[n];
            if (MODE == 0) {
                #pragma unroll
                for (int r = 0; r < 4; r++)
                    Cb[(size_t)(m0 + r) * 1024 + n] = f2bf(acc[mi][ni][r] + bv);
            } else if (MODE == 1) {
                int batch = m0 >> 11, mm = m0 & 2047;
                union { ushort u[4]; uint2v v2; } pk;
                #pragma unroll
                for (int r = 0; r < 4; r++) pk.u[r] = f2bf(acc[mi][ni][r] + bv);
                *(uint2v*)(Cb + (size_t)batch * 1024 * 2048 + (size_t)n * 2048 + mm) = pk.v2;
            } else {
                #pragma unroll
                for (int r = 0; r < 4; r++)
                    Cf[(size_t)(m0 + r) * 1024 + n] = acc[mi][ni][r] + bv;
            }
        }
    }
}

// ------------------- 4. fused head-softmax attention -----------------------
// grid (64 qtiles, 2 batches, 2 k-halves), 512 threads = 8 waves x 2 heads.
// Per 32-k step: St[k][q] = mfma(Kfrag, Qfrag) (swapped -> lane&15 = q),
// e = exp(St/32), Z[k][q] += e_h0+e_h1 (LDS atomics, all 16 heads),
// then P = e * rcp(Z) packs DIRECTLY into mfma_16x16x16 A-frags (k = 4*g+j).
__global__ __launch_bounds__(512, 2) void attn_kernel(
    const ushort* __restrict__ Qb, const ushort* __restrict__ Kb,
    const ushort* __restrict__ Vt, ushort* __restrict__ Op) {
    __shared__ float Zb[2][1056];  // [k(32)][q(32)] stride 33
    const int S = 2048;
    int tid = threadIdx.x, lane = tid & 63, wave = tid >> 6;
    int li = lane & 15, g = lane >> 4;
    int q0 = blockIdx.x * 32, b = blockIdx.y, ks = blockIdx.z;
    int h0 = wave * 2;
    const ushort* Qp = Qb + (size_t)(b * S + q0) * 1024;
    const ushort* Kp = Kb + (size_t)b * S * 1024 + (size_t)ks * 1024 * 1024;
    const ushort* Vp = Vt + (size_t)b * 1024 * S + (size_t)ks * 1024;

    // Q fragments (B-operand of swapped QK^T): lane holds q=li, 8 consec d
    short8 qf[2][2][2];  // [h][qsub][dchunk]
    #pragma unroll
    for (int h = 0; h < 2; h++)
        #pragma unroll
        for (int qs = 0; qs < 2; qs++)
            #pragma unroll
            for (int dc = 0; dc < 2; dc++)
                qf[h][qs][dc] = *(const short8*)(
                    Qp + (size_t)(qs * 16 + li) * 1024 + (h0 + h) * 64 + dc * 32 + g * 8);

    f32x4 oacc[2][2][4] = {};  // [h][qsub][dsub]

    for (int z = tid; z < 1056; z += 512) Zb[0][z] = 0.f;
    __syncthreads();

    for (int it = 0; it < 32; ++it) {
        int cur = it & 1;
        for (int z = tid; z < 1056; z += 512) Zb[cur ^ 1][z] = 0.f;
        int kb = it * 32;
        float e[2][2][2][4];  // [h][ksub][qsub][r]
        #pragma unroll
        for (int h = 0; h < 2; h++) {
            #pragma unroll
            for (int ksub = 0; ksub < 2; ksub++) {
                short8 kf0 = *(const short8*)(
                    Kp + (size_t)(kb + ksub * 16 + li) * 1024 + (h0 + h) * 64 + g * 8);
                short8 kf1 = *(const short8*)(
                    Kp + (size_t)(kb + ksub * 16 + li) * 1024 + (h0 + h) * 64 + 32 + g * 8);
                #pragma unroll
                for (int qs = 0; qs < 2; qs++) {
                    f32x4 st = {0.f, 0.f, 0.f, 0.f};
                    st = MFMA32(kf0, qf[h][qs][0], st);
                    st = MFMA32(kf1, qf[h][qs][1], st);
                    #pragma unroll
                    for (int r = 0; r < 4; r++)
                        e[h][ksub][qs][r] = __expf(st[r] * 0.03125f);
                }
            }
        }
        #pragma unroll
        for (int ksub = 0; ksub < 2; ksub++)
            #pragma unroll
            for (int qs = 0; qs < 2; qs++)
                #pragma unroll
                for (int r = 0; r < 4; r++) {
                    int zi = (ksub * 16 + g * 4 + r) * 33 + qs * 16 + li;
                    atomicAdd(&Zb[cur][zi], e[0][ksub][qs][r] + e[1][ksub][qs][r]);
                }
        __syncthreads();
        float rz[2][2][4];
        #pragma unroll
        for (int ksub = 0; ksub < 2; ksub++)
            #pragma unroll
            for (int qs = 0; qs < 2; qs++)
                #pragma unroll
                for (int r = 0; r < 4; r++) {
                    int zi = (ksub * 16 + g * 4 + r) * 33 + qs * 16 + li;
                    rz[ksub][qs][r] = __builtin_amdgcn_rcpf(Zb[cur][zi]);
                }
        short4v pf[2][2][2];  // [h][qsub][ksub] : A-frag of 16x16x16, k=4g+j
        #pragma unroll
        for (int h = 0; h < 2; h++)
            #pragma unroll
            for (int qs = 0; qs < 2; qs++)
                #pragma unroll
                for (int ksub = 0; ksub < 2; ksub++) {
                    short4v p;
                    #pragma unroll
                    for (int r = 0; r < 4; r++)
                        p[r] = (short)f2bf(e[h][ksub][qs][r] * rz[ksub][qs][r]);
                    pf[h][qs][ksub] = p;
                }
        #pragma unroll
        for (int h = 0; h < 2; h++)
            #pragma unroll
            for (int ksub = 0; ksub < 2; ksub++)
                #pragma unroll
                for (int ds = 0; ds < 4; ds++) {
                    short4v vf = *(const short4v*)(
                        Vp + (size_t)((h0 + h) * 64 + ds * 16 + li) * 2048 + kb + ksub * 16 + g * 4);
                    oacc[h][0][ds] = MFMA16(pf[h][0][ksub], vf, oacc[h][0][ds]);
                    oacc[h][1][ds] = MFMA16(pf[h][1][ksub], vf, oacc[h][1][ds]);
                }
        __syncthreads();
    }
    ushort* Oo = Op + (size_t)ks * 4096 * 1024 + (size_t)(b * S + q0) * 1024;
    #pragma unroll
    for (int h = 0; h < 2; h++)
        #pragma unroll
        for (int qs = 0; qs < 2; qs++)
            #pragma unroll
            for (int ds = 0; ds < 4; ds++)
                #pragma unroll
                for (int r = 0; r < 4; r++)
                    Oo[(size_t)(qs * 16 + g * 4 + r) * 1024 + (h0 + h) * 64 + ds * 16 + li] =
                        f2bf(oacc[h][qs][ds][r]);
}

// ------------------- 5. sum the two k-split partials -----------------------
__global__ __launch_bounds__(256) void sum_o_kernel(
    const ushort* __restrict__ o0, const ushort* __restrict__ o1,
    ushort* __restrict__ ob) {
    const size_t N = 4194304ull;
    size_t idx = ((size_t)blockIdx.x * 256 + threadIdx.x) * 8;
    for (; idx < N; idx += (size_t)gridDim.x * 256 * 8) {
        uint4v a = *(const uint4v*)(o0 + idx);
        uint4v b = *(const uint4v*)(o1 + idx);
        union { ushort u[8]; uint4v v4; } ua, ub, uo;
        ua.v4 = a; ub.v4 = b;
        #pragma unroll
        for (int j = 0; j < 8; j++) uo.u[j] = f2bf(bf2f(ua.u[j]) + bf2f(ub.u[j]));
        *(uint4v*)(ob + idx) = uo.v4;
    }
}

// ---------------------------------------------------------------------------
extern "C" void kernel_launch(void* const* d_in, const int* in_sizes, int n_in,
                              void* d_out, int out_size, void* d_ws, size_t ws_size,
                              hipStream_t stream) {
    const float* queries = (const float*)d_in[0];
    const float* keys    = (const float*)d_in[1];
    const float* values  = (const float*)d_in[2];
    const float* Wq = (const float*)d_in[3];
    const float* bq = (const float*)d_in[4];
    const float* Wk = (const float*)d_in[5];
    const float* bk = (const float*)d_in[6];
    const float* Wv = (const float*)d_in[7];
    const float* bv = (const float*)d_in[8];
    const float* Wo = (const float*)d_in[9];
    const float* bo = (const float*)d_in[10];
    float* out = (float*)d_out;

    // ws layout (ushort units). Requires ws_size >= 56 MB.
    ushort* Xb  = (ushort*)d_ws;            // [3][4096][1024]   (12M)
    ushort* Wt  = Xb + 12ull * 1024 * 1024; // [4][1024][1024]   (4M)
    ushort* Qb  = Wt + 4ull * 1024 * 1024;  // [4096][1024]      (4M)
    ushort* Kb  = Qb + 4ull * 1024 * 1024;  // [4096][1024]      (4M)
    ushort* Vtb = Kb + 4ull * 1024 * 1024;  // [2][1024][2048]   (4M)
    // O partials + Ob alias Xb (X is dead once the 3 projection GEMMs ran)
    ushort* Opart = Xb;                      // [2][4096][1024]  (8M)
    ushort* Ob    = Xb + 8ull * 1024 * 1024; // [4096][1024]     (4M)

    convert_x_kernel<<<2048, 256, 0, stream>>>(queries, keys, values, Xb);
    transpose_w_kernel<<<dim3(16, 16, 4), 256, 0, stream>>>(Wq, Wk, Wv, Wo, Wt);
    gemm_bt_kernel<0><<<dim3(8, 32), 256, 0, stream>>>(
        Xb, Wt, bq, Qb, nullptr);
    gemm_bt_kernel<0><<<dim3(8, 32), 256, 0, stream>>>(
        Xb + 4ull * 1024 * 1024, Wt + 1ull * 1024 * 1024, bk, Kb, nullptr);
    gemm_bt_kernel<1><<<dim3(8, 32), 256, 0, stream>>>(
        Xb + 8ull * 1024 * 1024, Wt + 2ull * 1024 * 1024, bv, Vtb, nullptr);
    attn_kernel<<<dim3(64, 2, 2), 512, 0, stream>>>(Qb, Kb, Vtb, Opart);
    sum_o_kernel<<<2048, 256, 0, stream>>>(Opart, Opart + 4ull * 1024 * 1024, Ob);
    gemm_bt_kernel<2><<<dim3(8, 32), 256, 0, stream>>>(
        Ob, Wt + 3ull * 1024 * 1024, bo, nullptr, out);
}